// Round 4
// baseline (281.476 us; speedup 1.0000x reference)
//
#include <hip/hip_runtime.h>
#include <math.h>

#define NODES 100000
#define EDGES 1600000
#define NBUCK 196     // ceil(NODES/512) dst-range buckets (512 nodes each)
#define BCAP2 12288   // capacity per bucket (mean 8163, +45 sigma slack)
#define EPB 4096      // edges per binning block
#define BINB 391      // ceil(EDGES/EPB)
#define GEMMB 1563    // ceil((NODES/16)/4)

typedef __attribute__((ext_vector_type(8))) short short8;
typedef __attribute__((ext_vector_type(4))) float floatx4;
typedef __attribute__((ext_vector_type(4))) unsigned uv4;

// group-of-8 reduction (xor 4,2,1 stays inside an aligned 8-lane group)
__device__ __forceinline__ float gsum8(float x) {
#pragma unroll
  for (int o = 4; o > 0; o >>= 1) x += __shfl_xor(x, o, 64);
  return x;
}

// bf16 <-> fp32 (RNE), no dependence on __hip_bfloat16 internals.
__device__ __forceinline__ short f2bf(float f) {
  union { float f; unsigned u; } v;
  v.f = f;
  unsigned r = 0x7fffu + ((v.u >> 16) & 1u);
  return (short)((v.u + r) >> 16);
}
__device__ __forceinline__ float bflo(unsigned p) {
  union { unsigned u; float f; } v; v.u = p << 16; return v.f;
}
__device__ __forceinline__ float bfhi(unsigned p) {
  union { unsigned u; float f; } v; v.u = p & 0xffff0000u; return v.f;
}
// scale a packed pair of bf16 by s, repack (RNE)
__device__ __forceinline__ unsigned scale2(unsigned p, float s) {
  float lo = bflo(p) * s, hi = bfhi(p) * s;
  unsigned ulo = (unsigned)(unsigned short)f2bf(lo);
  unsigned uhi = (unsigned)(unsigned short)f2bf(hi);
  return ulo | (uhi << 16);
}

// ---------- phase A body: LDS-staged binning with COALESCED bin writes ----------
// record = src (17b) | (dst & 511) << 17
#define BIN_SMEM (4 * 256 * 4 + EPB * 4 + EPB)
__device__ __forceinline__ void bin_body(char* smemraw, int b, const int* __restrict__ src,
                                         const int* __restrict__ dst, int* __restrict__ bins,
                                         int* __restrict__ gcur) {
  int* cnt = (int*)smemraw;            // 256
  int* gb = cnt + 256;                 // 256
  int* lb = gb + 256;                  // 256 (scan / exclusive base)
  int* lcur = lb + 256;                // 256
  int* rec = lcur + 256;               // EPB records
  unsigned char* rbk = (unsigned char*)(rec + EPB);  // EPB bucket ids
  int t = threadIdx.x;
  cnt[t] = 0;
  __syncthreads();
  int base = b * EPB;
  int nv = EDGES - base; if (nv > EPB) nv = EPB;
  int s[16], d[16];
#pragma unroll
  for (int j = 0; j < 16; ++j) {
    int e = base + j * 256 + t;  // coalesced
    if (e < EDGES) {
      s[j] = src[e];
      d[j] = dst[e];
      atomicAdd(&cnt[d[j] >> 9], 1);
    } else {
      d[j] = -1;
    }
  }
  __syncthreads();
  // block-local exclusive scan of bucket counts
  int c = cnt[t];
  lb[t] = c;
  __syncthreads();
  for (int o = 1; o < 256; o <<= 1) {
    int u = (t >= o) ? lb[t - o] : 0;
    __syncthreads();
    lb[t] += u;
    __syncthreads();
  }
  int ex = lb[t] - c;  // exclusive local base of bucket t
  gb[t] = (c > 0) ? atomicAdd(&gcur[t], c) : 0;  // ONE global atomic per (block,bucket)
  __syncthreads();
  lb[t] = ex;
  lcur[t] = ex;
  __syncthreads();
  // counting-sort records into LDS (bucket-contiguous)
#pragma unroll
  for (int j = 0; j < 16; ++j) {
    if (d[j] >= 0) {
      int bk = d[j] >> 9;
      int lp = atomicAdd(&lcur[bk], 1);  // LDS atomic (cheap)
      rec[lp] = s[j] | ((d[j] & 511) << 17);
      rbk[lp] = (unsigned char)bk;
    }
  }
  __syncthreads();
  // coalesced copy-out: consecutive i within a bucket -> consecutive global addresses
  for (int i = t; i < nv; i += 256) {
    int bk = rbk[i];
    int pos = gb[bk] + (i - lb[bk]);
    if (pos < BCAP2) bins[bk * BCAP2 + pos] = rec[i];
  }
}

// ---------- fill: bucket scan + histogram + rowptr/dinv + coalesced csr + hs PRESCALE ----------
// LDS: bsm 1KB + cnt 2KB + cur 2KB + wtot 16 + stage 48KB + dinvs 2KB = 56336 B
#define FILL_SMEM (256 * 4 + 512 * 4 + 512 * 4 + 4 * 4 + BCAP2 * 4 + 512 * 4)
__device__ __forceinline__ void fill_body(char* smemraw, int b, const int* __restrict__ bins,
                                          const int* __restrict__ gcur, int* __restrict__ rowptr,
                                          float* __restrict__ dinv, int* __restrict__ csr,
                                          short* __restrict__ hs) {
  int* bsm = (int*)smemraw;   // 256 ints
  int* cnt = bsm + 256;       // 512
  int* cur = cnt + 512;       // 512
  int* wtot = cur + 512;      // 4
  int* stage = wtot + 4;      // BCAP2
  float* dinvs = (float*)(stage + BCAP2);  // 512
  int t = threadIdx.x;
  int v = 0;
  if (t < NBUCK) { v = gcur[t]; if (v > BCAP2) v = BCAP2; }
  bsm[t] = v;
  cnt[t] = 0; cnt[t + 256] = 0;
  __syncthreads();
  for (int o = 1; o < 256; o <<= 1) {
    int u = (t >= o) ? bsm[t - o] : 0;
    __syncthreads();
    bsm[t] += u;
    __syncthreads();
  }
  if (b == 0 && t == NBUCK - 1) rowptr[NODES] = bsm[t];  // total placed
  int cb = gcur[b]; if (cb > BCAP2) cb = BCAP2;
  int bbase = bsm[b] - cb;  // exclusive global bucket base
  const int* bp = &bins[(size_t)b * BCAP2];
  for (int i = t; i < cb; i += 256)
    atomicAdd(&cnt[(bp[i] >> 17) & 511], 1);
  __syncthreads();
  int a0 = cnt[2 * t], a1 = cnt[2 * t + 1];
  int sum2 = a0 + a1;
  int lane = t & 63, w = t >> 6;
  int inc = sum2;
#pragma unroll
  for (int o = 1; o < 64; o <<= 1) {
    int u = __shfl_up(inc, o, 64);
    if (lane >= o) inc += u;
  }
  if (lane == 63) wtot[w] = inc;
  __syncthreads();
  int wpre = 0;
  for (int ww = 0; ww < w; ++ww) wpre += wtot[ww];
  int l0 = wpre + inc - sum2;   // LOCAL exclusive offset of node 2t within bucket
  int l1 = l0 + a0;
  int n0 = b * 512 + 2 * t, n1 = n0 + 1;
  float dv0 = rsqrtf((float)a0 + 1.0f), dv1 = rsqrtf((float)a1 + 1.0f);
  if (n0 < NODES) { rowptr[n0] = bbase + l0; dinv[n0] = dv0; }
  if (n1 < NODES) { rowptr[n1] = bbase + l1; dinv[n1] = dv1; }
  dinvs[2 * t] = dv0; dinvs[2 * t + 1] = dv1;
  cur[2 * t] = l0; cur[2 * t + 1] = l1;   // LOCAL positions -> stage in LDS
  __syncthreads();
  for (int i = t; i < cb; i += 256) {
    int pk = bp[i];
    int lp = atomicAdd(&cur[(pk >> 17) & 511], 1);
    stage[lp] = pk & 0x1FFFF;
  }
  __syncthreads();
  // fully coalesced csr write-out
  for (int i = t; i < cb; i += 256) csr[bbase + i] = stage[i];
  // in-place prescale of this bucket's hs rows: hs <- dinv ⊙ hs
  // (hs fully written by previous dispatch; block owns rows b*512..b*512+511)
  uv4* hv = (uv4*)hs;
  int nb = b * 512;
  for (int i = t; i < 4096; i += 256) {
    int row = i >> 3, ch = i & 7;
    int n = nb + row;
    if (n < NODES) {
      float s = dinvs[row];
      uv4 x = hv[(size_t)n * 8 + ch];
#pragma unroll
      for (int ww = 0; ww < 4; ++ww) x[ww] = scale2(x[ww], s);
      hv[(size_t)n * 8 + ch] = x;
    }
  }
}

// ---------- GEMM body: [N,128] fp32 @ [128,64] -> hs = bf16(x@W) (UNscaled) ----------
#define GEMM_SMEM (64 * 136 * 2)
__device__ __forceinline__ void gemm_body(char* smemraw, int tile0, const float* __restrict__ x,
                                          const float* __restrict__ W, short* __restrict__ hs) {
  constexpr int K = 128, KP = K + 8;
  short* wt = (short*)smemraw;  // W^T staged as bf16
  for (int idx = threadIdx.x; idx < K * 64; idx += 256) {
    int k = idx >> 6, n = idx & 63;
    wt[n * KP + k] = f2bf(W[idx]);
  }
  __syncthreads();
  int wid = threadIdx.x >> 6, lane = threadIdx.x & 63;
  int tile = tile0 + wid;
  if (tile * 16 >= NODES) return;
  int m = lane & 15, q = lane >> 4;

  short8 bfr[4][K / 32];
#pragma unroll
  for (int ct = 0; ct < 4; ++ct)
#pragma unroll
    for (int ks = 0; ks < K / 32; ++ks)
      bfr[ct][ks] = *reinterpret_cast<const short8*>(&wt[(ct * 16 + m) * KP + ks * 32 + q * 8]);

  floatx4 acc[4];
#pragma unroll
  for (int ct = 0; ct < 4; ++ct) acc[ct] = {0.f, 0.f, 0.f, 0.f};
  int r0 = tile * 16;
#pragma unroll
  for (int ks = 0; ks < K / 32; ++ks) {
    const float* xp = &x[(size_t)(r0 + m) * K + ks * 32 + q * 8];
    floatx4 a0 = *reinterpret_cast<const floatx4*>(xp);
    floatx4 a1 = *reinterpret_cast<const floatx4*>(xp + 4);
    short8 af;
#pragma unroll
    for (int j = 0; j < 4; ++j) { af[j] = f2bf(a0[j]); af[4 + j] = f2bf(a1[j]); }
#pragma unroll
    for (int ct = 0; ct < 4; ++ct)
      acc[ct] = __builtin_amdgcn_mfma_f32_16x16x32_bf16(af, bfr[ct][ks], acc[ct], 0, 0, 0);
  }
  // C/D: col = lane&15, row = (lane>>4)*4 + reg   [measured m89/m91]
#pragma unroll
  for (int ct = 0; ct < 4; ++ct)
#pragma unroll
    for (int r = 0; r < 4; ++r) {
      int row = r0 + q * 4 + r, col = ct * 16 + m;
      hs[row * 64 + col] = f2bf(acc[ct][r]);
    }
}

// ---------- W^T bf16 precompute for the agg kernels (64x72 padded layout) ----------
__device__ __forceinline__ void prepw_body(int p, const float* __restrict__ W2,
                                           const float* __restrict__ W3,
                                           short* __restrict__ wt2, short* __restrict__ wt3) {
  const float* W = (p < 4) ? W2 : W3;
  short* wt = (p < 4) ? wt2 : wt3;
  int b0 = (p & 3) * 1024;
  for (int i = threadIdx.x; i < 1024; i += 256) {
    int e = b0 + i;
    int k = e >> 6, n = e & 63;
    wt[n * 72 + k] = f2bf(W[e]);
  }
}

// ---------- 24-deep gather aggregation (hs prescaled: pure adds) ----------
// acc = hs[n] + sum_j hs[src_j];  wave trip count = max-of-8 ceil(deg/24) ~= 1.15
__device__ __forceinline__ void do_agg24(const uv4* __restrict__ hsv, const int* __restrict__ csr,
                                         int n, int e0, int e1, int lane, float acc[8]) {
  int q = lane & 7, srcb = lane & 0x38;
  uv4 sv = hsv[(size_t)n * 8 + q];  // self row, features q*8..q*8+7
#pragma unroll
  for (int w = 0; w < 4; ++w) { acc[2 * w] = bflo(sv[w]); acc[2 * w + 1] = bfhi(sv[w]); }
  for (int base = e0; base < e1; base += 24) {
    int rem = e1 - base;
    int cnt = rem > 24 ? 24 : rem;
    // three csr picks per lane (q, q+8, q+16), clamped in-row (always valid)
    int p0 = base + q, p1 = p0 + 8, p2 = p0 + 16;
    int i0 = csr[p0 < e1 ? p0 : e0];
    int i1 = csr[p1 < e1 ? p1 : e0];
    int i2 = csr[p2 < e1 ? p2 : e0];
    uv4 v[24];  // 96 VGPR of gathers in flight (static indexing only)
#pragma unroll
    for (int j = 0; j < 8; ++j) {
      int s = __shfl(i0, srcb | j, 64);
      v[j] = hsv[(size_t)s * 8 + q];
    }
#pragma unroll
    for (int j = 0; j < 8; ++j) {
      int s = __shfl(i1, srcb | j, 64);
      v[8 + j] = hsv[(size_t)s * 8 + q];
    }
#pragma unroll
    for (int j = 0; j < 8; ++j) {
      int s = __shfl(i2, srcb | j, 64);
      v[16 + j] = hsv[(size_t)s * 8 + q];
    }
    // pin: all 24 gather issues stay ABOVE the accumulate (no sinking)
    __builtin_amdgcn_sched_barrier(0);
    if (cnt == 24) {
#pragma unroll
      for (int j = 0; j < 24; ++j)
#pragma unroll
        for (int w = 0; w < 4; ++w) { acc[2 * w] += bflo(v[j][w]); acc[2 * w + 1] += bfhi(v[j][w]); }
    } else {
#pragma unroll
      for (int j = 0; j < 24; ++j)
        if (j < cnt)
#pragma unroll
          for (int w = 0; w < 4; ++w) { acc[2 * w] += bflo(v[j][w]); acc[2 * w + 1] += bfhi(v[j][w]); }
    }
  }
}

// ---------- fused aggregate + bias + LN + GELU + next-layer GEMM ----------
// hs is dinv-prescaled; writes hsn = dinv ⊙ (u @ W)  [row-scale commute]
__global__ __launch_bounds__(256, 1) void k_aggg(const short* __restrict__ hs,
                                                 const float* __restrict__ dinv,
                                                 const int* __restrict__ rowptr,
                                                 const int* __restrict__ csr,
                                                 const float* __restrict__ bias,
                                                 const float* __restrict__ gam,
                                                 const float* __restrict__ bet,
                                                 const short* __restrict__ wtg,  // W^T bf16 [64*72]
                                                 short* __restrict__ hsn) {
  __shared__ __align__(16) short wt[64 * 72];  // W^T bf16
  __shared__ __align__(16) short ut[32 * 72];  // (dinv*u) tile bf16
  int t = threadIdx.x;
  {
    const int* wp = (const int*)wtg;
    int* wd = (int*)wt;
    for (int idx = t; idx < 2304; idx += 256) wd[idx] = wp[idx];  // straight dword copy
  }
  const uv4* hsv = (const uv4*)hs;
  int lane = t & 63, wid = t >> 6;
  int g = lane >> 3, q = lane & 7;
  int nb0 = blockIdx.x * 32;
  int r = wid * 8 + g;                      // row in 32-node tile
  int n = nb0 + r;                          // grid 3125 exact -> always valid
  int e0 = rowptr[n], e1 = rowptr[n + 1];
  float dn = dinv[n];
  float acc[8];
  do_agg24(hsv, csr, n, e0, e1, lane, acc);

  const floatx4* bi4 = (const floatx4*)bias;
  floatx4 b0 = bi4[q * 2], b1 = bi4[q * 2 + 1];
#pragma unroll
  for (int f = 0; f < 4; ++f) { acc[f] = acc[f] * dn + b0[f]; acc[f + 4] = acc[f + 4] * dn + b1[f]; }

  float lsum = 0.f;
#pragma unroll
  for (int f = 0; f < 8; ++f) lsum += acc[f];
  float mu = gsum8(lsum) * (1.0f / 64.0f);
  float d[8], lvar = 0.f;
#pragma unroll
  for (int f = 0; f < 8; ++f) { d[f] = acc[f] - mu; lvar += d[f] * d[f]; }
  float rs = rsqrtf(gsum8(lvar) * (1.0f / 64.0f) + 1e-5f);
  const floatx4* gm4 = (const floatx4*)gam;
  const floatx4* bt4 = (const floatx4*)bet;
  floatx4 g0 = gm4[q * 2], g1 = gm4[q * 2 + 1];
  floatx4 t0 = bt4[q * 2], t1 = bt4[q * 2 + 1];
  short8 us;
#pragma unroll
  for (int f = 0; f < 8; ++f) {
    float gv = (f < 4) ? g0[f] : g1[f - 4];
    float tv = (f < 4) ? t0[f] : t1[f - 4];
    float vv = d[f] * rs * gv + tv;
    float u = 0.5f * vv * (1.0f + erff(vv * 0.70710678118654752f));  // exact GELU
    us[f] = f2bf(u * dn);                   // prescale for next layer (commute)
  }
  *reinterpret_cast<short8*>(&ut[r * 72 + q * 8]) = us;
  __syncthreads();

  // in-block GEMM: 32x64 tile @ W (64x64) -> hsn rows nb0..nb0+31
  int m = lane & 15, q2 = lane >> 4;
  int tile = wid >> 1, cb = (wid & 1) * 2;  // wave -> (row-tile, ct pair)
  short8 bfr[2][2];
#pragma unroll
  for (int ct = 0; ct < 2; ++ct)
#pragma unroll
    for (int ks = 0; ks < 2; ++ks)
      bfr[ct][ks] = *reinterpret_cast<const short8*>(&wt[((cb + ct) * 16 + m) * 72 + ks * 32 + q2 * 8]);
  floatx4 ac[2];
#pragma unroll
  for (int ct = 0; ct < 2; ++ct) ac[ct] = {0.f, 0.f, 0.f, 0.f};
#pragma unroll
  for (int ks = 0; ks < 2; ++ks) {
    short8 af = *reinterpret_cast<const short8*>(&ut[(tile * 16 + m) * 72 + ks * 32 + q2 * 8]);
#pragma unroll
    for (int ct = 0; ct < 2; ++ct)
      ac[ct] = __builtin_amdgcn_mfma_f32_16x16x32_bf16(af, bfr[ct][ks], ac[ct], 0, 0, 0);
  }
#pragma unroll
  for (int ct = 0; ct < 2; ++ct)
#pragma unroll
    for (int rr = 0; rr < 4; ++rr) {
      int row = nb0 + tile * 16 + q2 * 4 + rr, col = (cb + ct) * 16 + m;
      hsn[row * 64 + col] = f2bf(ac[ct][rr]);
    }
}

// ---------- final layer: aggregate + bias + LN + GELU + head ----------
__global__ __launch_bounds__(256, 1) void k_agg_fin(const short* __restrict__ hs,
                                                    const float* __restrict__ dinv,
                                                    const int* __restrict__ rowptr,
                                                    const int* __restrict__ csr,
                                                    const float* __restrict__ bias,
                                                    const float* __restrict__ gam,
                                                    const float* __restrict__ bet,
                                                    const float* __restrict__ Wh,
                                                    const float* __restrict__ bh,
                                                    float* __restrict__ out) {
  const uv4* hsv = (const uv4*)hs;
  int lane = threadIdx.x & 63, wid = threadIdx.x >> 6;
  int g = lane >> 3, q = lane & 7;
  int n = blockIdx.x * 32 + wid * 8 + g;
  int e0 = rowptr[n], e1 = rowptr[n + 1];
  float dn = dinv[n];
  float acc[8];
  do_agg24(hsv, csr, n, e0, e1, lane, acc);
  const floatx4* bi4 = (const floatx4*)bias;
  floatx4 b0 = bi4[q * 2], b1 = bi4[q * 2 + 1];
#pragma unroll
  for (int f = 0; f < 4; ++f) { acc[f] = acc[f] * dn + b0[f]; acc[f + 4] = acc[f + 4] * dn + b1[f]; }
  float lsum = 0.f;
#pragma unroll
  for (int f = 0; f < 8; ++f) lsum += acc[f];
  float mu = gsum8(lsum) * (1.0f / 64.0f);
  float d[8], lvar = 0.f;
#pragma unroll
  for (int f = 0; f < 8; ++f) { d[f] = acc[f] - mu; lvar += d[f] * d[f]; }
  float rs = rsqrtf(gsum8(lvar) * (1.0f / 64.0f) + 1e-5f);
  const floatx4* gm4 = (const floatx4*)gam;
  const floatx4* bt4 = (const floatx4*)bet;
  floatx4 g0 = gm4[q * 2], g1 = gm4[q * 2 + 1];
  floatx4 t0 = bt4[q * 2], t1 = bt4[q * 2 + 1];
  const floatx4* wh4 = (const floatx4*)Wh;
  floatx4 w0 = wh4[q * 2], w1 = wh4[q * 2 + 1];
  float lp = 0.f;
#pragma unroll
  for (int f = 0; f < 8; ++f) {
    float gv = (f < 4) ? g0[f] : g1[f - 4];
    float tv = (f < 4) ? t0[f] : t1[f - 4];
    float wv = (f < 4) ? w0[f] : w1[f - 4];
    float vv = d[f] * rs * gv + tv;
    float u = 0.5f * vv * (1.0f + erff(vv * 0.70710678118654752f));
    lp += u * wv;
  }
  float p = gsum8(lp);
  if (q == 0) out[n] = p + bh[0];
}

// ---------- fused dispatch wrappers ----------
// dispatch 1: binning (391) || FULL gemm (1563) || W2/W3 transpose (8)
__global__ __launch_bounds__(256) void k_pre1(const int* __restrict__ src, const int* __restrict__ dst,
                                              int* __restrict__ bins, int* __restrict__ gcur,
                                              const float* __restrict__ x, const float* __restrict__ W1,
                                              short* __restrict__ hs,
                                              const float* __restrict__ W2, const float* __restrict__ W3,
                                              short* __restrict__ wt2, short* __restrict__ wt3) {
  __shared__ __align__(16) char smem[BIN_SMEM];  // 24576 >= GEMM_SMEM 17408
  int b = blockIdx.x;
  if (b < BINB) bin_body(smem, b, src, dst, bins, gcur);
  else if (b < BINB + GEMMB) gemm_body(smem, (b - BINB) * 4, x, W1, hs);
  else prepw_body(b - BINB - GEMMB, W2, W3, wt2, wt3);
}

// dispatch 2: csr fill + per-bucket hs prescale (196 blocks, big LDS stage)
__global__ __launch_bounds__(256) void k_pre2(const int* __restrict__ bins, const int* __restrict__ gcur,
                                              int* __restrict__ rowptr, float* __restrict__ dinv,
                                              int* __restrict__ csr, short* __restrict__ hs) {
  __shared__ __align__(16) char smem[FILL_SMEM];
  fill_body(smem, blockIdx.x, bins, gcur, rowptr, dinv, csr, hs);
}

// standalone fallback wrappers (ws too small to un-alias bins)
__global__ __launch_bounds__(256) void k_bin2(const int* src, const int* dst, int* bins, int* gcur) {
  __shared__ __align__(16) char smem[BIN_SMEM];
  bin_body(smem, blockIdx.x, src, dst, bins, gcur);
}
__global__ __launch_bounds__(256) void k_fillb2(const int* bins, const int* gcur, int* rowptr,
                                                float* dinv, int* csr, short* hs) {
  __shared__ __align__(16) char smem[FILL_SMEM];
  fill_body(smem, blockIdx.x, bins, gcur, rowptr, dinv, csr, hs);
}
__global__ __launch_bounds__(256) void k_gemm(const float* x, const float* W, short* hs) {
  __shared__ __align__(16) char smem[GEMM_SMEM];
  gemm_body(smem, blockIdx.x * 4, x, W, hs);
}
__global__ __launch_bounds__(256) void k_prepw(const float* W2, const float* W3, short* wt2, short* wt3) {
  prepw_body(blockIdx.x, W2, W3, wt2, wt3);
}

extern "C" void kernel_launch(void* const* d_in, const int* in_sizes, int n_in,
                              void* d_out, int out_size, void* d_ws, size_t ws_size,
                              hipStream_t stream) {
  const float* x  = (const float*)d_in[0];
  const int* ei   = (const int*)d_in[1];
  const float* W1 = (const float*)d_in[2];
  const float* b1 = (const float*)d_in[3];
  const float* g1 = (const float*)d_in[4];
  const float* be1= (const float*)d_in[5];
  const float* W2 = (const float*)d_in[6];
  const float* b2 = (const float*)d_in[7];
  const float* g2 = (const float*)d_in[8];
  const float* be2= (const float*)d_in[9];
  const float* W3 = (const float*)d_in[10];
  const float* b3 = (const float*)d_in[11];
  const float* g3 = (const float*)d_in[12];
  const float* be3= (const float*)d_in[13];
  const float* Wh = (const float*)d_in[14];
  const float* bh = (const float*)d_in[15];
  const int* srcp = ei;
  const int* dstp = ei + EDGES;

  char* ws = (char*)d_ws;
  size_t off = 0;
  auto take = [&](size_t bytes) {
    char* p = ws + off;
    off = (off + bytes + 255) & ~(size_t)255;
    return p;
  };
  float* dinv = (float*)take((size_t)NODES * 4);
  int* rowptr = (int*)take((size_t)(NODES + 1) * 4);
  int* csr    = (int*)take((size_t)EDGES * 4);
  short* hs_a = (short*)take((size_t)NODES * 64 * 2);   // 12.8 MB
  short* hs_b = (short*)take((size_t)NODES * 64 * 2);   // 12.8 MB
  short* wt2  = (short*)take((size_t)64 * 72 * 2);      // W2^T bf16 (padded)
  short* wt3  = (short*)take((size_t)64 * 72 * 2);      // W3^T bf16

  size_t bins_sz = (size_t)NBUCK * BCAP2 * 4;           // 9.63 MB
  bool overlap = (ws_size >= off + bins_sz + 4096);
  int* bins; int* gcur;
  if (overlap) {
    bins = (int*)take(bins_sz);
    gcur = (int*)take((size_t)NBUCK * 4);
  } else {
    // fall back to aliasing (bins consumed by fill before any GEMM writes hs)
    bins = (int*)hs_a;
    gcur = (int*)hs_b;
  }

  (void)hipMemsetAsync(gcur, 0, (size_t)NBUCK * 4, stream);
  if (overlap) {
    k_pre1<<<BINB + GEMMB + 8, 256, 0, stream>>>(srcp, dstp, bins, gcur, x, W1, hs_a, W2, W3, wt2, wt3);
    k_pre2<<<NBUCK, 256, 0, stream>>>(bins, gcur, rowptr, dinv, csr, hs_a);
  } else {
    // fallback order: gemm must precede fill (fill prescales hs_a in place)
    k_bin2<<<BINB, 256, 0, stream>>>(srcp, dstp, bins, gcur);
    k_gemm<<<GEMMB, 256, 0, stream>>>(x, W1, hs_a);
    k_prepw<<<8, 256, 0, stream>>>(W2, W3, wt2, wt3);
    k_fillb2<<<NBUCK, 256, 0, stream>>>(bins, gcur, rowptr, dinv, csr, hs_a);
  }
  // all layers: hs prescaled by dinv (layer 1 via pre2's fused prescale)
  k_aggg<<<NODES / 32, 256, 0, stream>>>(hs_a, dinv, rowptr, csr, b1, g1, be1, wt2, hs_b);
  k_aggg<<<NODES / 32, 256, 0, stream>>>(hs_b, dinv, rowptr, csr, b2, g2, be2, wt3, hs_a);
  k_agg_fin<<<NODES / 32, 256, 0, stream>>>(hs_a, dinv, rowptr, csr, b3, g3, be3, Wh, bh, (float*)d_out);
}

// Round 5
// 274.206 us; speedup vs baseline: 1.0265x; 1.0265x over previous
//
#include <hip/hip_runtime.h>
#include <math.h>

#define NODES 100000
#define EDGES 1600000
#define NBUCK 196     // ceil(NODES/512) dst-range buckets (512 nodes each)
#define BCAP2 12288   // capacity per bucket (mean 8163, +45 sigma slack)
#define EPB 4096      // edges per binning block
#define BINB 391      // ceil(EDGES/EPB)
#define GEMMB 1563    // ceil((NODES/16)/4)
#define GSTRIDE 16    // gcur padded: one counter per 64B line (atomic line contention)

typedef __attribute__((ext_vector_type(8))) short short8;
typedef __attribute__((ext_vector_type(4))) float floatx4;
typedef __attribute__((ext_vector_type(4))) unsigned uv4;

// group-of-8 reduction (xor 4,2,1 stays inside an aligned 8-lane group)
__device__ __forceinline__ float gsum8(float x) {
#pragma unroll
  for (int o = 4; o > 0; o >>= 1) x += __shfl_xor(x, o, 64);
  return x;
}

// bf16 <-> fp32 (RNE), no dependence on __hip_bfloat16 internals.
__device__ __forceinline__ short f2bf(float f) {
  union { float f; unsigned u; } v;
  v.f = f;
  unsigned r = 0x7fffu + ((v.u >> 16) & 1u);
  return (short)((v.u + r) >> 16);
}
__device__ __forceinline__ float bflo(unsigned p) {
  union { unsigned u; float f; } v; v.u = p << 16; return v.f;
}
__device__ __forceinline__ float bfhi(unsigned p) {
  union { unsigned u; float f; } v; v.u = p & 0xffff0000u; return v.f;
}
// scale a packed pair of bf16 by s, repack (RNE)
__device__ __forceinline__ unsigned scale2(unsigned p, float s) {
  float lo = bflo(p) * s, hi = bfhi(p) * s;
  unsigned ulo = (unsigned)(unsigned short)f2bf(lo);
  unsigned uhi = (unsigned)(unsigned short)f2bf(hi);
  return ulo | (uhi << 16);
}

// ---------- phase A body: LDS-staged binning with COALESCED bin writes ----------
// record = src (17b) | (dst & 511) << 17
// LDS: cnt/gb/lb/lcur (4x256) + wt4(8) + rec (EPB) + rbk (EPB bytes)
#define BIN_SMEM ((4 * 256 + 8) * 4 + EPB * 4 + EPB)
__device__ __forceinline__ void bin_body(char* smemraw, int b, const int* __restrict__ src,
                                         const int* __restrict__ dst, int* __restrict__ bins,
                                         int* __restrict__ gcur) {
  int* cnt = (int*)smemraw;            // 256
  int* gb = cnt + 256;                 // 256
  int* lb = gb + 256;                  // 256 (exclusive local base)
  int* lcur = lb + 256;                // 256
  int* wt4 = lcur + 256;               // 8 (wave totals)
  int* rec = wt4 + 8;                  // EPB records
  unsigned char* rbk = (unsigned char*)(rec + EPB);  // EPB bucket ids
  int t = threadIdx.x;
  cnt[t] = 0;
  __syncthreads();
  int base = b * EPB;
  int nv = EDGES - base; if (nv > EPB) nv = EPB;
  int s[16], d[16];
#pragma unroll
  for (int j = 0; j < 16; ++j) {
    int e = base + j * 256 + t;  // coalesced
    if (e < EDGES) {
      s[j] = src[e];
      d[j] = dst[e];
      atomicAdd(&cnt[d[j] >> 9], 1);
    } else {
      d[j] = -1;
    }
  }
  __syncthreads();
  // wave-level exclusive scan of the 256 bucket counts (2 barriers, not 16)
  int c = cnt[t];
  int lane = t & 63, w = t >> 6;
  int inc = c;
#pragma unroll
  for (int o = 1; o < 64; o <<= 1) {
    int u = __shfl_up(inc, o, 64);
    if (lane >= o) inc += u;
  }
  if (lane == 63) wt4[w] = inc;
  __syncthreads();
  int wpre = 0;
  for (int ww = 0; ww < w; ++ww) wpre += wt4[ww];
  int ex = wpre + inc - c;  // exclusive local base of bucket t
  gb[t] = (c > 0) ? atomicAdd(&gcur[t * GSTRIDE], c) : 0;  // ONE global atomic per (block,bucket)
  lb[t] = ex;
  lcur[t] = ex;
  __syncthreads();
  // counting-sort records into LDS (bucket-contiguous)
#pragma unroll
  for (int j = 0; j < 16; ++j) {
    if (d[j] >= 0) {
      int bk = d[j] >> 9;
      int lp = atomicAdd(&lcur[bk], 1);  // LDS atomic (cheap)
      rec[lp] = s[j] | ((d[j] & 511) << 17);
      rbk[lp] = (unsigned char)bk;
    }
  }
  __syncthreads();
  // coalesced copy-out: consecutive i within a bucket -> consecutive global addresses
  for (int i = t; i < nv; i += 256) {
    int bk = rbk[i];
    int pos = gb[bk] + (i - lb[bk]);
    if (pos < BCAP2) bins[bk * BCAP2 + pos] = rec[i];
  }
}

// ---------- fill: bucket scan + histogram + rowptr/dinv + coalesced csr + hs PRESCALE ----------
// 512 threads (only 196 blocks exist -> per-thread trip counts halved vs 256)
#define FILL_T 512
// LDS: bsm 256 + cnt 512 + cur 512 + wtot 8 + stage BCAP2 + dinvs 512 (ints)
#define FILL_SMEM ((256 + 512 + 512 + 8 + BCAP2 + 512) * 4)
__device__ __forceinline__ void fill_body(char* smemraw, int b, const int* __restrict__ bins,
                                          const int* __restrict__ gcur, int* __restrict__ rowptr,
                                          float* __restrict__ dinv, int* __restrict__ csr,
                                          short* __restrict__ hs) {
  int* bsm = (int*)smemraw;   // 256 (inclusive bucket-count scan)
  int* cnt = bsm + 256;       // 512
  int* cur = cnt + 512;       // 512
  int* wtot = cur + 512;      // 8
  int* stage = wtot + 8;      // BCAP2
  float* dinvs = (float*)(stage + BCAP2);  // 512
  int t = threadIdx.x;
  int lane = t & 63, w = t >> 6;
  // wave-scan of 256 bucket counts on the first 4 waves (2 barriers)
  if (t < 256) {
    int v = 0;
    if (t < NBUCK) { v = gcur[t * GSTRIDE]; if (v > BCAP2) v = BCAP2; }
    int inc = v;
#pragma unroll
    for (int o = 1; o < 64; o <<= 1) {
      int u = __shfl_up(inc, o, 64);
      if (lane >= o) inc += u;
    }
    if (lane == 63) wtot[w] = inc;
    cnt[t] = 0; cnt[t + 256] = 0;
    bsm[t] = v;  // temp: raw count
  }
  __syncthreads();
  if (t < 256) {
    int wpre = 0;
    for (int ww = 0; ww < w; ++ww) wpre += wtot[ww];
    // inclusive scan value
    int v = bsm[t];
    int inc = v;
#pragma unroll
    for (int o = 1; o < 64; o <<= 1) {
      int u = __shfl_up(inc, o, 64);
      if (lane >= o) inc += u;
    }
    bsm[t] = wpre + inc;  // inclusive
  }
  __syncthreads();
  if (b == 0 && t == NBUCK - 1) rowptr[NODES] = bsm[t];  // total placed
  int cb = gcur[b * GSTRIDE]; if (cb > BCAP2) cb = BCAP2;
  int bbase = bsm[b] - cb;  // exclusive global bucket base
  const int* bp = &bins[(size_t)b * BCAP2];
  for (int i = t; i < cb; i += FILL_T)
    atomicAdd(&cnt[(bp[i] >> 17) & 511], 1);
  __syncthreads();
  // per-node positions: first 256 threads own node pairs (2t, 2t+1)
  if (t < 256) {
    int a0 = cnt[2 * t], a1 = cnt[2 * t + 1];
    int sum2 = a0 + a1;
    int inc = sum2;
#pragma unroll
    for (int o = 1; o < 64; o <<= 1) {
      int u = __shfl_up(inc, o, 64);
      if (lane >= o) inc += u;
    }
    if (lane == 63) wtot[w] = inc;
    // stash for after barrier
    cur[2 * t] = inc - sum2;  // provisional (wave-local exclusive)
    cur[2 * t + 1] = a0;      // carry a0
    dinvs[2 * t] = __int_as_float(a0);
    dinvs[2 * t + 1] = __int_as_float(a1);
  }
  __syncthreads();
  if (t < 256) {
    int wpre = 0;
    for (int ww = 0; ww < w; ++ww) wpre += wtot[ww];
    int a0 = __float_as_int(dinvs[2 * t]), a1 = __float_as_int(dinvs[2 * t + 1]);
    int l0 = wpre + cur[2 * t];
    int l1 = l0 + a0;
    int n0 = b * 512 + 2 * t, n1 = n0 + 1;
    float dv0 = rsqrtf((float)a0 + 1.0f), dv1 = rsqrtf((float)a1 + 1.0f);
    if (n0 < NODES) { rowptr[n0] = bbase + l0; dinv[n0] = dv0; }
    if (n1 < NODES) { rowptr[n1] = bbase + l1; dinv[n1] = dv1; }
    dinvs[2 * t] = dv0; dinvs[2 * t + 1] = dv1;
    cur[2 * t] = l0; cur[2 * t + 1] = l1;   // LOCAL positions -> stage in LDS
  }
  __syncthreads();
  for (int i = t; i < cb; i += FILL_T) {
    int pk = bp[i];
    int lp = atomicAdd(&cur[(pk >> 17) & 511], 1);
    stage[lp] = pk & 0x1FFFF;
  }
  __syncthreads();
  // fully coalesced csr write-out
  for (int i = t; i < cb; i += FILL_T) csr[bbase + i] = stage[i];
  // in-place prescale of this bucket's hs rows: hs <- dinv ⊙ hs
  // (hs fully written by previous dispatch; block owns rows b*512..b*512+511)
  uv4* hv = (uv4*)hs;
  int nb = b * 512;
  for (int i = t; i < 4096; i += FILL_T) {
    int row = i >> 3, ch = i & 7;
    int n = nb + row;
    if (n < NODES) {
      float s = dinvs[row];
      uv4 x = hv[(size_t)n * 8 + ch];
#pragma unroll
      for (int ww = 0; ww < 4; ++ww) x[ww] = scale2(x[ww], s);
      hv[(size_t)n * 8 + ch] = x;
    }
  }
}

// ---------- GEMM body: [N,128] fp32 @ [128,64] -> hs = bf16(x@W) (UNscaled) ----------
#define GEMM_SMEM (64 * 136 * 2)
__device__ __forceinline__ void gemm_body(char* smemraw, int tile0, const float* __restrict__ x,
                                          const float* __restrict__ W, short* __restrict__ hs) {
  constexpr int K = 128, KP = K + 8;
  short* wt = (short*)smemraw;  // W^T staged as bf16
  for (int idx = threadIdx.x; idx < K * 64; idx += 256) {
    int k = idx >> 6, n = idx & 63;
    wt[n * KP + k] = f2bf(W[idx]);
  }
  __syncthreads();
  int wid = threadIdx.x >> 6, lane = threadIdx.x & 63;
  int tile = tile0 + wid;
  if (tile * 16 >= NODES) return;
  int m = lane & 15, q = lane >> 4;

  short8 bfr[4][K / 32];
#pragma unroll
  for (int ct = 0; ct < 4; ++ct)
#pragma unroll
    for (int ks = 0; ks < K / 32; ++ks)
      bfr[ct][ks] = *reinterpret_cast<const short8*>(&wt[(ct * 16 + m) * KP + ks * 32 + q * 8]);

  floatx4 acc[4];
#pragma unroll
  for (int ct = 0; ct < 4; ++ct) acc[ct] = {0.f, 0.f, 0.f, 0.f};
  int r0 = tile * 16;
#pragma unroll
  for (int ks = 0; ks < K / 32; ++ks) {
    const float* xp = &x[(size_t)(r0 + m) * K + ks * 32 + q * 8];
    floatx4 a0 = *reinterpret_cast<const floatx4*>(xp);
    floatx4 a1 = *reinterpret_cast<const floatx4*>(xp + 4);
    short8 af;
#pragma unroll
    for (int j = 0; j < 4; ++j) { af[j] = f2bf(a0[j]); af[4 + j] = f2bf(a1[j]); }
#pragma unroll
    for (int ct = 0; ct < 4; ++ct)
      acc[ct] = __builtin_amdgcn_mfma_f32_16x16x32_bf16(af, bfr[ct][ks], acc[ct], 0, 0, 0);
  }
  // C/D: col = lane&15, row = (lane>>4)*4 + reg   [measured m89/m91]
#pragma unroll
  for (int ct = 0; ct < 4; ++ct)
#pragma unroll
    for (int r = 0; r < 4; ++r) {
      int row = r0 + q * 4 + r, col = ct * 16 + m;
      hs[row * 64 + col] = f2bf(acc[ct][r]);
    }
}

// ---------- W^T bf16 precompute for the agg kernels (64x72 padded layout) ----------
__device__ __forceinline__ void prepw_body(int p, const float* __restrict__ W2,
                                           const float* __restrict__ W3,
                                           short* __restrict__ wt2, short* __restrict__ wt3) {
  const float* W = (p < 4) ? W2 : W3;
  short* wt = (p < 4) ? wt2 : wt3;
  int b0 = (p & 3) * 1024;
  for (int i = threadIdx.x; i < 1024; i += 256) {
    int e = b0 + i;
    int k = e >> 6, n = e & 63;
    wt[n * 72 + k] = f2bf(W[e]);
  }
}

// ---------- ROUND-0 aggregation loop (proven 42.6us / VGPR 52); hs prescaled: pure adds ----------
__device__ __forceinline__ void do_agg(const uv4* __restrict__ hsv, const int* __restrict__ csr,
                                       int n, int e0, int e1, int lane, float acc[8]) {
  int q = lane & 7, srcb = lane & 0x38;
  uv4 sv = hsv[(size_t)n * 8 + q];  // self row, features q*8..q*8+7
#pragma unroll
  for (int w = 0; w < 4; ++w) { acc[2 * w] = bflo(sv[w]); acc[2 * w + 1] = bfhi(sv[w]); }
  for (int base = e0; base < e1; base += 8) {
    int cnt = e1 - base;
    if (cnt > 8) cnt = 8;
    int a = base + (q < cnt ? q : 0);       // clamp: always valid in-row index
    int sidx = csr[a];
    int s[8];
#pragma unroll
    for (int j = 0; j < 8; ++j) s[j] = __shfl(sidx, srcb | j, 64);
    uv4 v[8];
#pragma unroll
    for (int j = 0; j < 8; ++j) v[j] = hsv[(size_t)s[j] * 8 + q];
    if (cnt == 8) {
#pragma unroll
      for (int j = 0; j < 8; ++j)
#pragma unroll
        for (int w = 0; w < 4; ++w) { acc[2 * w] += bflo(v[j][w]); acc[2 * w + 1] += bfhi(v[j][w]); }
    } else {
#pragma unroll
      for (int j = 0; j < 8; ++j)
        if (j < cnt)
#pragma unroll
          for (int w = 0; w < 4; ++w) { acc[2 * w] += bflo(v[j][w]); acc[2 * w + 1] += bfhi(v[j][w]); }
    }
  }
}

// ---------- fused aggregate + bias + LN + GELU + next-layer GEMM ----------
// hs is dinv-prescaled; writes hsn = dinv ⊙ (u @ W)  [row-scale commute]
__global__ __launch_bounds__(256) void k_aggg(const short* __restrict__ hs,
                                              const float* __restrict__ dinv,
                                              const int* __restrict__ rowptr,
                                              const int* __restrict__ csr,
                                              const float* __restrict__ bias,
                                              const float* __restrict__ gam,
                                              const float* __restrict__ bet,
                                              const short* __restrict__ wtg,  // W^T bf16 [64*72]
                                              short* __restrict__ hsn) {
  __shared__ __align__(16) short wt[64 * 72];  // W^T bf16
  __shared__ __align__(16) short ut[32 * 72];  // (dinv*u) tile bf16
  int t = threadIdx.x;
  {
    const int* wp = (const int*)wtg;
    int* wd = (int*)wt;
    for (int idx = t; idx < 2304; idx += 256) wd[idx] = wp[idx];  // straight dword copy
  }
  const uv4* hsv = (const uv4*)hs;
  int lane = t & 63, wid = t >> 6;
  int g = lane >> 3, q = lane & 7;
  int nb0 = blockIdx.x * 32;
  int r = wid * 8 + g;                      // row in 32-node tile
  int n = nb0 + r;                          // grid 3125 exact -> always valid
  int e0 = rowptr[n], e1 = rowptr[n + 1];
  float dn = dinv[n];
  float acc[8];
  do_agg(hsv, csr, n, e0, e1, lane, acc);

  const floatx4* bi4 = (const floatx4*)bias;
  floatx4 b0 = bi4[q * 2], b1 = bi4[q * 2 + 1];
#pragma unroll
  for (int f = 0; f < 4; ++f) { acc[f] = acc[f] * dn + b0[f]; acc[f + 4] = acc[f + 4] * dn + b1[f]; }

  float lsum = 0.f;
#pragma unroll
  for (int f = 0; f < 8; ++f) lsum += acc[f];
  float mu = gsum8(lsum) * (1.0f / 64.0f);
  float d[8], lvar = 0.f;
#pragma unroll
  for (int f = 0; f < 8; ++f) { d[f] = acc[f] - mu; lvar += d[f] * d[f]; }
  float rs = rsqrtf(gsum8(lvar) * (1.0f / 64.0f) + 1e-5f);
  const floatx4* gm4 = (const floatx4*)gam;
  const floatx4* bt4 = (const floatx4*)bet;
  floatx4 g0 = gm4[q * 2], g1 = gm4[q * 2 + 1];
  floatx4 t0 = bt4[q * 2], t1 = bt4[q * 2 + 1];
  short8 us;
#pragma unroll
  for (int f = 0; f < 8; ++f) {
    float gv = (f < 4) ? g0[f] : g1[f - 4];
    float tv = (f < 4) ? t0[f] : t1[f - 4];
    float vv = d[f] * rs * gv + tv;
    float u = 0.5f * vv * (1.0f + erff(vv * 0.70710678118654752f));  // exact GELU
    us[f] = f2bf(u * dn);                   // prescale for next layer (commute)
  }
  *reinterpret_cast<short8*>(&ut[r * 72 + q * 8]) = us;
  __syncthreads();

  // in-block GEMM: 32x64 tile @ W (64x64) -> hsn rows nb0..nb0+31
  int m = lane & 15, q2 = lane >> 4;
  int tile = wid >> 1, cb = (wid & 1) * 2;  // wave -> (row-tile, ct pair)
  short8 bfr[2][2];
#pragma unroll
  for (int ct = 0; ct < 2; ++ct)
#pragma unroll
    for (int ks = 0; ks < 2; ++ks)
      bfr[ct][ks] = *reinterpret_cast<const short8*>(&wt[((cb + ct) * 16 + m) * 72 + ks * 32 + q2 * 8]);
  floatx4 ac[2];
#pragma unroll
  for (int ct = 0; ct < 2; ++ct) ac[ct] = {0.f, 0.f, 0.f, 0.f};
#pragma unroll
  for (int ks = 0; ks < 2; ++ks) {
    short8 af = *reinterpret_cast<const short8*>(&ut[(tile * 16 + m) * 72 + ks * 32 + q2 * 8]);
#pragma unroll
    for (int ct = 0; ct < 2; ++ct)
      ac[ct] = __builtin_amdgcn_mfma_f32_16x16x32_bf16(af, bfr[ct][ks], ac[ct], 0, 0, 0);
  }
#pragma unroll
  for (int ct = 0; ct < 2; ++ct)
#pragma unroll
    for (int rr = 0; rr < 4; ++rr) {
      int row = nb0 + tile * 16 + q2 * 4 + rr, col = (cb + ct) * 16 + m;
      hsn[row * 64 + col] = f2bf(ac[ct][rr]);
    }
}

// ---------- final layer: aggregate + bias + LN + GELU + head ----------
__global__ __launch_bounds__(256) void k_agg_fin(const short* __restrict__ hs,
                                                 const float* __restrict__ dinv,
                                                 const int* __restrict__ rowptr,
                                                 const int* __restrict__ csr,
                                                 const float* __restrict__ bias,
                                                 const float* __restrict__ gam,
                                                 const float* __restrict__ bet,
                                                 const float* __restrict__ Wh,
                                                 const float* __restrict__ bh,
                                                 float* __restrict__ out) {
  const uv4* hsv = (const uv4*)hs;
  int lane = threadIdx.x & 63, wid = threadIdx.x >> 6;
  int g = lane >> 3, q = lane & 7;
  int n = blockIdx.x * 32 + wid * 8 + g;
  int e0 = rowptr[n], e1 = rowptr[n + 1];
  float dn = dinv[n];
  float acc[8];
  do_agg(hsv, csr, n, e0, e1, lane, acc);
  const floatx4* bi4 = (const floatx4*)bias;
  floatx4 b0 = bi4[q * 2], b1 = bi4[q * 2 + 1];
#pragma unroll
  for (int f = 0; f < 4; ++f) { acc[f] = acc[f] * dn + b0[f]; acc[f + 4] = acc[f + 4] * dn + b1[f]; }
  float lsum = 0.f;
#pragma unroll
  for (int f = 0; f < 8; ++f) lsum += acc[f];
  float mu = gsum8(lsum) * (1.0f / 64.0f);
  float d[8], lvar = 0.f;
#pragma unroll
  for (int f = 0; f < 8; ++f) { d[f] = acc[f] - mu; lvar += d[f] * d[f]; }
  float rs = rsqrtf(gsum8(lvar) * (1.0f / 64.0f) + 1e-5f);
  const floatx4* gm4 = (const floatx4*)gam;
  const floatx4* bt4 = (const floatx4*)bet;
  floatx4 g0 = gm4[q * 2], g1 = gm4[q * 2 + 1];
  floatx4 t0 = bt4[q * 2], t1 = bt4[q * 2 + 1];
  const floatx4* wh4 = (const floatx4*)Wh;
  floatx4 w0 = wh4[q * 2], w1 = wh4[q * 2 + 1];
  float lp = 0.f;
#pragma unroll
  for (int f = 0; f < 8; ++f) {
    float gv = (f < 4) ? g0[f] : g1[f - 4];
    float tv = (f < 4) ? t0[f] : t1[f - 4];
    float wv = (f < 4) ? w0[f] : w1[f - 4];
    float vv = d[f] * rs * gv + tv;
    float u = 0.5f * vv * (1.0f + erff(vv * 0.70710678118654752f));
    lp += u * wv;
  }
  float p = gsum8(lp);
  if (q == 0) out[n] = p + bh[0];
}

// ---------- fused dispatch wrappers ----------
// dispatch 1: binning (391) || FULL gemm (1563) || W2/W3 transpose (8)
__global__ __launch_bounds__(256) void k_pre1(const int* __restrict__ src, const int* __restrict__ dst,
                                              int* __restrict__ bins, int* __restrict__ gcur,
                                              const float* __restrict__ x, const float* __restrict__ W1,
                                              short* __restrict__ hs,
                                              const float* __restrict__ W2, const float* __restrict__ W3,
                                              short* __restrict__ wt2, short* __restrict__ wt3) {
  __shared__ __align__(16) char smem[BIN_SMEM];  // 24608 >= GEMM_SMEM 17408
  int b = blockIdx.x;
  if (b < BINB) bin_body(smem, b, src, dst, bins, gcur);
  else if (b < BINB + GEMMB) gemm_body(smem, (b - BINB) * 4, x, W1, hs);
  else prepw_body(b - BINB - GEMMB, W2, W3, wt2, wt3);
}

// dispatch 2: csr fill + per-bucket hs prescale (196 blocks x 512 threads)
__global__ __launch_bounds__(FILL_T) void k_pre2(const int* __restrict__ bins, const int* __restrict__ gcur,
                                                 int* __restrict__ rowptr, float* __restrict__ dinv,
                                                 int* __restrict__ csr, short* __restrict__ hs) {
  __shared__ __align__(16) char smem[FILL_SMEM];
  fill_body(smem, blockIdx.x, bins, gcur, rowptr, dinv, csr, hs);
}

// standalone fallback wrappers (ws too small to un-alias bins)
__global__ __launch_bounds__(256) void k_bin2(const int* src, const int* dst, int* bins, int* gcur) {
  __shared__ __align__(16) char smem[BIN_SMEM];
  bin_body(smem, blockIdx.x, src, dst, bins, gcur);
}
__global__ __launch_bounds__(FILL_T) void k_fillb2(const int* bins, const int* gcur, int* rowptr,
                                                   float* dinv, int* csr, short* hs) {
  __shared__ __align__(16) char smem[FILL_SMEM];
  fill_body(smem, blockIdx.x, bins, gcur, rowptr, dinv, csr, hs);
}
__global__ __launch_bounds__(256) void k_gemm(const float* x, const float* W, short* hs) {
  __shared__ __align__(16) char smem[GEMM_SMEM];
  gemm_body(smem, blockIdx.x * 4, x, W, hs);
}
__global__ __launch_bounds__(256) void k_prepw(const float* W2, const float* W3, short* wt2, short* wt3) {
  prepw_body(blockIdx.x, W2, W3, wt2, wt3);
}

extern "C" void kernel_launch(void* const* d_in, const int* in_sizes, int n_in,
                              void* d_out, int out_size, void* d_ws, size_t ws_size,
                              hipStream_t stream) {
  const float* x  = (const float*)d_in[0];
  const int* ei   = (const int*)d_in[1];
  const float* W1 = (const float*)d_in[2];
  const float* b1 = (const float*)d_in[3];
  const float* g1 = (const float*)d_in[4];
  const float* be1= (const float*)d_in[5];
  const float* W2 = (const float*)d_in[6];
  const float* b2 = (const float*)d_in[7];
  const float* g2 = (const float*)d_in[8];
  const float* be2= (const float*)d_in[9];
  const float* W3 = (const float*)d_in[10];
  const float* b3 = (const float*)d_in[11];
  const float* g3 = (const float*)d_in[12];
  const float* be3= (const float*)d_in[13];
  const float* Wh = (const float*)d_in[14];
  const float* bh = (const float*)d_in[15];
  const int* srcp = ei;
  const int* dstp = ei + EDGES;

  char* ws = (char*)d_ws;
  size_t off = 0;
  auto take = [&](size_t bytes) {
    char* p = ws + off;
    off = (off + bytes + 255) & ~(size_t)255;
    return p;
  };
  float* dinv = (float*)take((size_t)NODES * 4);
  int* rowptr = (int*)take((size_t)(NODES + 1) * 4);
  int* csr    = (int*)take((size_t)EDGES * 4);
  short* hs_a = (short*)take((size_t)NODES * 64 * 2);   // 12.8 MB
  short* hs_b = (short*)take((size_t)NODES * 64 * 2);   // 12.8 MB
  short* wt2  = (short*)take((size_t)64 * 72 * 2);      // W2^T bf16 (padded)
  short* wt3  = (short*)take((size_t)64 * 72 * 2);      // W3^T bf16

  size_t bins_sz = (size_t)NBUCK * BCAP2 * 4;           // 9.63 MB
  size_t gcur_sz = (size_t)NBUCK * GSTRIDE * 4;         // 12.5 KB (line-padded)
  bool overlap = (ws_size >= off + bins_sz + gcur_sz + 4096);
  int* bins; int* gcur;
  if (overlap) {
    bins = (int*)take(bins_sz);
    gcur = (int*)take(gcur_sz);
  } else {
    // fall back to aliasing (bins consumed by fill before any GEMM writes hs)
    bins = (int*)hs_a;
    gcur = (int*)hs_b;
  }

  (void)hipMemsetAsync(gcur, 0, gcur_sz, stream);
  if (overlap) {
    k_pre1<<<BINB + GEMMB + 8, 256, 0, stream>>>(srcp, dstp, bins, gcur, x, W1, hs_a, W2, W3, wt2, wt3);
    k_pre2<<<NBUCK, FILL_T, 0, stream>>>(bins, gcur, rowptr, dinv, csr, hs_a);
  } else {
    // fallback order: gemm must precede fill (fill prescales hs_a in place)
    k_bin2<<<BINB, 256, 0, stream>>>(srcp, dstp, bins, gcur);
    k_gemm<<<GEMMB, 256, 0, stream>>>(x, W1, hs_a);
    k_prepw<<<8, 256, 0, stream>>>(W2, W3, wt2, wt3);
    k_fillb2<<<NBUCK, FILL_T, 0, stream>>>(bins, gcur, rowptr, dinv, csr, hs_a);
  }
  // all layers: hs prescaled by dinv (layer 1 via pre2's fused prescale)
  k_aggg<<<NODES / 32, 256, 0, stream>>>(hs_a, dinv, rowptr, csr, b1, g1, be1, wt2, hs_b);
  k_aggg<<<NODES / 32, 256, 0, stream>>>(hs_b, dinv, rowptr, csr, b2, g2, be2, wt3, hs_a);
  k_agg_fin<<<NODES / 32, 256, 0, stream>>>(hs_a, dinv, rowptr, csr, b3, g3, be3, Wh, bh, (float*)d_out);
}

// Round 6
// 266.002 us; speedup vs baseline: 1.0582x; 1.0308x over previous
//
#include <hip/hip_runtime.h>
#include <math.h>

#define NODES 100000
#define EDGES 1600000
#define NBUCK 196     // ceil(NODES/512) dst-range buckets (512 nodes each)
#define BCAP2 12288   // capacity per bucket (mean 8163, +45 sigma slack)
#define EPB 4096      // edges per binning block
#define BINB 391      // ceil(EDGES/EPB)
#define GEMMB 1563    // ceil((NODES/16)/4)

typedef __attribute__((ext_vector_type(8))) short short8;
typedef __attribute__((ext_vector_type(4))) float floatx4;
typedef __attribute__((ext_vector_type(4))) unsigned uv4;

// group-of-8 reduction (xor 4,2,1 stays inside an aligned 8-lane group)
__device__ __forceinline__ float gsum8(float x) {
#pragma unroll
  for (int o = 4; o > 0; o >>= 1) x += __shfl_xor(x, o, 64);
  return x;
}

// bf16 <-> fp32 (RNE), no dependence on __hip_bfloat16 internals.
__device__ __forceinline__ short f2bf(float f) {
  union { float f; unsigned u; } v;
  v.f = f;
  unsigned r = 0x7fffu + ((v.u >> 16) & 1u);
  return (short)((v.u + r) >> 16);
}
__device__ __forceinline__ float bflo(unsigned p) {
  union { unsigned u; float f; } v; v.u = p << 16; return v.f;
}
__device__ __forceinline__ float bfhi(unsigned p) {
  union { unsigned u; float f; } v; v.u = p & 0xffff0000u; return v.f;
}

// ---------- phase A body: LDS-staged binning with COALESCED bin writes ----------
// record = src (17b) | (dst & 511) << 17
#define BIN_SMEM (4 * 256 * 4 + EPB * 4 + EPB)
__device__ __forceinline__ void bin_body(char* smemraw, int b, const int* __restrict__ src,
                                         const int* __restrict__ dst, int* __restrict__ bins,
                                         int* __restrict__ gcur) {
  int* cnt = (int*)smemraw;            // 256
  int* gb = cnt + 256;                 // 256
  int* lb = gb + 256;                  // 256 (scan / exclusive base)
  int* lcur = lb + 256;                // 256
  int* rec = lcur + 256;               // EPB records
  unsigned char* rbk = (unsigned char*)(rec + EPB);  // EPB bucket ids
  int t = threadIdx.x;
  cnt[t] = 0;
  __syncthreads();
  int base = b * EPB;
  int nv = EDGES - base; if (nv > EPB) nv = EPB;
  int s[16], d[16];
#pragma unroll
  for (int j = 0; j < 16; ++j) {
    int e = base + j * 256 + t;  // coalesced
    if (e < EDGES) {
      s[j] = src[e];
      d[j] = dst[e];
      atomicAdd(&cnt[d[j] >> 9], 1);
    } else {
      d[j] = -1;
    }
  }
  __syncthreads();
  // block-local exclusive scan of bucket counts
  int c = cnt[t];
  lb[t] = c;
  __syncthreads();
  for (int o = 1; o < 256; o <<= 1) {
    int u = (t >= o) ? lb[t - o] : 0;
    __syncthreads();
    lb[t] += u;
    __syncthreads();
  }
  int ex = lb[t] - c;  // exclusive local base of bucket t
  gb[t] = (c > 0) ? atomicAdd(&gcur[t], c) : 0;  // ONE global atomic per (block,bucket)
  __syncthreads();
  lb[t] = ex;
  lcur[t] = ex;
  __syncthreads();
  // counting-sort records into LDS (bucket-contiguous)
#pragma unroll
  for (int j = 0; j < 16; ++j) {
    if (d[j] >= 0) {
      int bk = d[j] >> 9;
      int lp = atomicAdd(&lcur[bk], 1);  // LDS atomic (cheap)
      rec[lp] = s[j] | ((d[j] & 511) << 17);
      rbk[lp] = (unsigned char)bk;
    }
  }
  __syncthreads();
  // coalesced copy-out: consecutive i within a bucket -> consecutive global addresses
  for (int i = t; i < nv; i += 256) {
    int bk = rbk[i];
    int pos = gb[bk] + (i - lb[bk]);
    if (pos < BCAP2) bins[bk * BCAP2 + pos] = rec[i];
  }
}

// ---------- fill: bucket scan + histogram + rowptr/dinv + LDS-staged COALESCED csr ----------
#define FILL_SMEM (256 * 4 + 512 * 4 + 512 * 4 + 4 * 4 + BCAP2 * 4)
__device__ __forceinline__ void fill_body(char* smemraw, int b, const int* __restrict__ bins,
                                          const int* __restrict__ gcur, int* __restrict__ rowptr,
                                          float* __restrict__ dinv, int* __restrict__ csr) {
  int* bsm = (int*)smemraw;   // 256 ints
  int* cnt = bsm + 256;       // 512
  int* cur = cnt + 512;       // 512
  int* wtot = cur + 512;      // 4
  int* stage = wtot + 4;      // BCAP2
  int t = threadIdx.x;
  int v = 0;
  if (t < NBUCK) { v = gcur[t]; if (v > BCAP2) v = BCAP2; }
  bsm[t] = v;
  cnt[t] = 0; cnt[t + 256] = 0;
  __syncthreads();
  for (int o = 1; o < 256; o <<= 1) {
    int u = (t >= o) ? bsm[t - o] : 0;
    __syncthreads();
    bsm[t] += u;
    __syncthreads();
  }
  if (b == 0 && t == NBUCK - 1) rowptr[NODES] = bsm[t];  // total placed
  int cb = gcur[b]; if (cb > BCAP2) cb = BCAP2;
  int bbase = bsm[b] - cb;  // exclusive global bucket base
  const int* bp = &bins[(size_t)b * BCAP2];
  for (int i = t; i < cb; i += 256)
    atomicAdd(&cnt[(bp[i] >> 17) & 511], 1);
  __syncthreads();
  int a0 = cnt[2 * t], a1 = cnt[2 * t + 1];
  int sum2 = a0 + a1;
  int lane = t & 63, w = t >> 6;
  int inc = sum2;
#pragma unroll
  for (int o = 1; o < 64; o <<= 1) {
    int u = __shfl_up(inc, o, 64);
    if (lane >= o) inc += u;
  }
  if (lane == 63) wtot[w] = inc;
  __syncthreads();
  int wpre = 0;
  for (int ww = 0; ww < w; ++ww) wpre += wtot[ww];
  int l0 = wpre + inc - sum2;   // LOCAL exclusive offset of node 2t within bucket
  int l1 = l0 + a0;
  int n0 = b * 512 + 2 * t, n1 = n0 + 1;
  if (n0 < NODES) { rowptr[n0] = bbase + l0; dinv[n0] = rsqrtf((float)a0 + 1.0f); }
  if (n1 < NODES) { rowptr[n1] = bbase + l1; dinv[n1] = rsqrtf((float)a1 + 1.0f); }
  cur[2 * t] = l0; cur[2 * t + 1] = l1;   // LOCAL positions -> stage in LDS
  __syncthreads();
  for (int i = t; i < cb; i += 256) {
    int pk = bp[i];
    int lp = atomicAdd(&cur[(pk >> 17) & 511], 1);
    stage[lp] = pk & 0x1FFFF;
  }
  __syncthreads();
  // fully coalesced csr write-out
  for (int i = t; i < cb; i += 256) csr[bbase + i] = stage[i];
}

// ---------- GEMM body: [N,128] fp32 @ [128,64] -> hs = bf16(x@W) (UNscaled) ----------
#define GEMM_SMEM (64 * 136 * 2)
__device__ __forceinline__ void gemm_body(char* smemraw, int tile0, const float* __restrict__ x,
                                          const float* __restrict__ W, short* __restrict__ hs) {
  constexpr int K = 128, KP = K + 8;
  short* wt = (short*)smemraw;  // W^T staged as bf16
  for (int idx = threadIdx.x; idx < K * 64; idx += 256) {
    int k = idx >> 6, n = idx & 63;
    wt[n * KP + k] = f2bf(W[idx]);
  }
  __syncthreads();
  int wid = threadIdx.x >> 6, lane = threadIdx.x & 63;
  int tile = tile0 + wid;
  if (tile * 16 >= NODES) return;
  int m = lane & 15, q = lane >> 4;

  short8 bfr[4][K / 32];
#pragma unroll
  for (int ct = 0; ct < 4; ++ct)
#pragma unroll
    for (int ks = 0; ks < K / 32; ++ks)
      bfr[ct][ks] = *reinterpret_cast<const short8*>(&wt[(ct * 16 + m) * KP + ks * 32 + q * 8]);

  floatx4 acc[4];
#pragma unroll
  for (int ct = 0; ct < 4; ++ct) acc[ct] = {0.f, 0.f, 0.f, 0.f};
  int r0 = tile * 16;
#pragma unroll
  for (int ks = 0; ks < K / 32; ++ks) {
    const float* xp = &x[(size_t)(r0 + m) * K + ks * 32 + q * 8];
    floatx4 a0 = *reinterpret_cast<const floatx4*>(xp);
    floatx4 a1 = *reinterpret_cast<const floatx4*>(xp + 4);
    short8 af;
#pragma unroll
    for (int j = 0; j < 4; ++j) { af[j] = f2bf(a0[j]); af[4 + j] = f2bf(a1[j]); }
#pragma unroll
    for (int ct = 0; ct < 4; ++ct)
      acc[ct] = __builtin_amdgcn_mfma_f32_16x16x32_bf16(af, bfr[ct][ks], acc[ct], 0, 0, 0);
  }
  // C/D: col = lane&15, row = (lane>>4)*4 + reg   [measured m89/m91]
#pragma unroll
  for (int ct = 0; ct < 4; ++ct)
#pragma unroll
    for (int r = 0; r < 4; ++r) {
      int row = r0 + q * 4 + r, col = ct * 16 + m;
      hs[row * 64 + col] = f2bf(acc[ct][r]);
    }
}

// ---------- ROUND-0 aggregation loop, weight-parameterized ----------
// acc = [PRESCALED ? 1 : dn]*hs[n] + sum_j w_j * hs[src_j],  w_j = PRESCALED?1:dinv[src_j]
template <bool PRESCALED>
__device__ __forceinline__ void do_agg(const uv4* __restrict__ hsv, const float* __restrict__ dinv,
                                       const int* __restrict__ csr, int n, int e0, int e1,
                                       int lane, float dn, float acc[8]) {
  int q = lane & 7, srcb = lane & 0x38;
  uv4 sv = hsv[(size_t)n * 8 + q];  // self row, features q*8..q*8+7
#pragma unroll
  for (int w = 0; w < 4; ++w) {
    float lo = bflo(sv[w]), hi = bfhi(sv[w]);
    if constexpr (PRESCALED) { acc[2 * w] = lo; acc[2 * w + 1] = hi; }
    else { acc[2 * w] = lo * dn; acc[2 * w + 1] = hi * dn; }
  }
  for (int base = e0; base < e1; base += 8) {
    int cnt = e1 - base;
    if (cnt > 8) cnt = 8;
    int a = base + (q < cnt ? q : 0);       // clamp: always valid in-row index
    int sidx = csr[a];
    float gq = 1.0f;
    if constexpr (!PRESCALED) gq = dinv[sidx];
    int s[8]; float wj[8];
#pragma unroll
    for (int j = 0; j < 8; ++j) {
      s[j] = __shfl(sidx, srcb | j, 64);
      if constexpr (!PRESCALED) {
        float bj = __shfl(gq, srcb | j, 64);
        wj[j] = (j < cnt) ? bj : 0.0f;
      } else {
        wj[j] = 1.0f;  // unused in PRESCALED accumulate below
      }
    }
    uv4 v[8];
#pragma unroll
    for (int j = 0; j < 8; ++j) v[j] = hsv[(size_t)s[j] * 8 + q];
    if constexpr (PRESCALED) {
      if (cnt == 8) {
#pragma unroll
        for (int j = 0; j < 8; ++j)
#pragma unroll
          for (int w = 0; w < 4; ++w) { acc[2 * w] += bflo(v[j][w]); acc[2 * w + 1] += bfhi(v[j][w]); }
      } else {
#pragma unroll
        for (int j = 0; j < 8; ++j)
          if (j < cnt)
#pragma unroll
            for (int w = 0; w < 4; ++w) { acc[2 * w] += bflo(v[j][w]); acc[2 * w + 1] += bfhi(v[j][w]); }
      }
    } else {
#pragma unroll
      for (int j = 0; j < 8; ++j)
#pragma unroll
        for (int w = 0; w < 4; ++w) {
          acc[2 * w]     += wj[j] * bflo(v[j][w]);
          acc[2 * w + 1] += wj[j] * bfhi(v[j][w]);
        }
    }
  }
}

// ---------- fused aggregate + bias + LN + GELU + next-layer GEMM ----------
// PRESCALED: hs rows already carry dinv[src]; else gather dinv per edge.
// W staged IN-KERNEL from fp32 (round-0 entry code: restores the VGPR-52 schedule)
// writes hsn = dinv ⊙ (u @ W)  [row-scale commute]
template <bool PRESCALED>
__global__ __launch_bounds__(256) void k_aggg(const short* __restrict__ hs,
                                              const float* __restrict__ dinv,
                                              const int* __restrict__ rowptr,
                                              const int* __restrict__ csr,
                                              const float* __restrict__ bias,
                                              const float* __restrict__ gam,
                                              const float* __restrict__ bet,
                                              const float* __restrict__ W,   // next-layer W fp32 [64x64]
                                              short* __restrict__ hsn) {
  __shared__ __align__(16) short wt[64 * 72];  // W^T bf16
  __shared__ __align__(16) short ut[32 * 72];  // (dinv*u) tile bf16
  int t = threadIdx.x;
  for (int idx = t; idx < 4096; idx += 256) {
    int k = idx >> 6, n = idx & 63;
    wt[n * 72 + k] = f2bf(W[idx]);
  }
  const uv4* hsv = (const uv4*)hs;
  int lane = t & 63, wid = t >> 6;
  int g = lane >> 3, q = lane & 7;
  int nb0 = blockIdx.x * 32;
  int r = wid * 8 + g;                      // row in 32-node tile
  int n = nb0 + r;                          // grid 3125 exact -> always valid
  int e0 = rowptr[n], e1 = rowptr[n + 1];
  float dn = dinv[n];
  float acc[8];
  do_agg<PRESCALED>(hsv, dinv, csr, n, e0, e1, lane, dn, acc);

  const floatx4* bi4 = (const floatx4*)bias;
  floatx4 b0 = bi4[q * 2], b1 = bi4[q * 2 + 1];
#pragma unroll
  for (int f = 0; f < 4; ++f) { acc[f] = acc[f] * dn + b0[f]; acc[f + 4] = acc[f + 4] * dn + b1[f]; }

  float lsum = 0.f;
#pragma unroll
  for (int f = 0; f < 8; ++f) lsum += acc[f];
  float mu = gsum8(lsum) * (1.0f / 64.0f);
  float d[8], lvar = 0.f;
#pragma unroll
  for (int f = 0; f < 8; ++f) { d[f] = acc[f] - mu; lvar += d[f] * d[f]; }
  float rs = rsqrtf(gsum8(lvar) * (1.0f / 64.0f) + 1e-5f);
  const floatx4* gm4 = (const floatx4*)gam;
  const floatx4* bt4 = (const floatx4*)bet;
  floatx4 g0 = gm4[q * 2], g1 = gm4[q * 2 + 1];
  floatx4 t0 = bt4[q * 2], t1 = bt4[q * 2 + 1];
  short8 us;
#pragma unroll
  for (int f = 0; f < 8; ++f) {
    float gv = (f < 4) ? g0[f] : g1[f - 4];
    float tv = (f < 4) ? t0[f] : t1[f - 4];
    float vv = d[f] * rs * gv + tv;
    float u = 0.5f * vv * (1.0f + erff(vv * 0.70710678118654752f));  // exact GELU
    us[f] = f2bf(u * dn);                   // prescale for next layer (commute)
  }
  *reinterpret_cast<short8*>(&ut[r * 72 + q * 8]) = us;
  __syncthreads();

  // in-block GEMM: 32x64 tile @ W (64x64) -> hsn rows nb0..nb0+31
  int m = lane & 15, q2 = lane >> 4;
  int tile = wid >> 1, cb = (wid & 1) * 2;  // wave -> (row-tile, ct pair)
  short8 bfr[2][2];
#pragma unroll
  for (int ct = 0; ct < 2; ++ct)
#pragma unroll
    for (int ks = 0; ks < 2; ++ks)
      bfr[ct][ks] = *reinterpret_cast<const short8*>(&wt[((cb + ct) * 16 + m) * 72 + ks * 32 + q2 * 8]);
  floatx4 ac[2];
#pragma unroll
  for (int ct = 0; ct < 2; ++ct) ac[ct] = {0.f, 0.f, 0.f, 0.f};
#pragma unroll
  for (int ks = 0; ks < 2; ++ks) {
    short8 af = *reinterpret_cast<const short8*>(&ut[(tile * 16 + m) * 72 + ks * 32 + q2 * 8]);
#pragma unroll
    for (int ct = 0; ct < 2; ++ct)
      ac[ct] = __builtin_amdgcn_mfma_f32_16x16x32_bf16(af, bfr[ct][ks], ac[ct], 0, 0, 0);
  }
#pragma unroll
  for (int ct = 0; ct < 2; ++ct)
#pragma unroll
    for (int rr = 0; rr < 4; ++rr) {
      int row = nb0 + tile * 16 + q2 * 4 + rr, col = (cb + ct) * 16 + m;
      hsn[row * 64 + col] = f2bf(ac[ct][rr]);
    }
}

// ---------- final layer: aggregate + bias + LN + GELU + head ----------
__global__ __launch_bounds__(256) void k_agg_fin(const short* __restrict__ hs,
                                                 const float* __restrict__ dinv,
                                                 const int* __restrict__ rowptr,
                                                 const int* __restrict__ csr,
                                                 const float* __restrict__ bias,
                                                 const float* __restrict__ gam,
                                                 const float* __restrict__ bet,
                                                 const float* __restrict__ Wh,
                                                 const float* __restrict__ bh,
                                                 float* __restrict__ out) {
  const uv4* hsv = (const uv4*)hs;
  int lane = threadIdx.x & 63, wid = threadIdx.x >> 6;
  int g = lane >> 3, q = lane & 7;
  int n = blockIdx.x * 32 + wid * 8 + g;
  int e0 = rowptr[n], e1 = rowptr[n + 1];
  float dn = dinv[n];
  float acc[8];
  do_agg<true>(hsv, dinv, csr, n, e0, e1, lane, dn, acc);
  const floatx4* bi4 = (const floatx4*)bias;
  floatx4 b0 = bi4[q * 2], b1 = bi4[q * 2 + 1];
#pragma unroll
  for (int f = 0; f < 4; ++f) { acc[f] = acc[f] * dn + b0[f]; acc[f + 4] = acc[f + 4] * dn + b1[f]; }
  float lsum = 0.f;
#pragma unroll
  for (int f = 0; f < 8; ++f) lsum += acc[f];
  float mu = gsum8(lsum) * (1.0f / 64.0f);
  float d[8], lvar = 0.f;
#pragma unroll
  for (int f = 0; f < 8; ++f) { d[f] = acc[f] - mu; lvar += d[f] * d[f]; }
  float rs = rsqrtf(gsum8(lvar) * (1.0f / 64.0f) + 1e-5f);
  const floatx4* gm4 = (const floatx4*)gam;
  const floatx4* bt4 = (const floatx4*)bet;
  floatx4 g0 = gm4[q * 2], g1 = gm4[q * 2 + 1];
  floatx4 t0 = bt4[q * 2], t1 = bt4[q * 2 + 1];
  const floatx4* wh4 = (const floatx4*)Wh;
  floatx4 w0 = wh4[q * 2], w1 = wh4[q * 2 + 1];
  float lp = 0.f;
#pragma unroll
  for (int f = 0; f < 8; ++f) {
    float gv = (f < 4) ? g0[f] : g1[f - 4];
    float tv = (f < 4) ? t0[f] : t1[f - 4];
    float wv = (f < 4) ? w0[f] : w1[f - 4];
    float vv = d[f] * rs * gv + tv;
    float u = 0.5f * vv * (1.0f + erff(vv * 0.70710678118654752f));
    lp += u * wv;
  }
  float p = gsum8(lp);
  if (q == 0) out[n] = p + bh[0];
}

// ---------- fused dispatch wrappers ----------
// dispatch 1: binning (391) || FULL gemm (1563)
__global__ __launch_bounds__(256) void k_pre1(const int* __restrict__ src, const int* __restrict__ dst,
                                              int* __restrict__ bins, int* __restrict__ gcur,
                                              const float* __restrict__ x, const float* __restrict__ W1,
                                              short* __restrict__ hs) {
  __shared__ __align__(16) char smem[BIN_SMEM];  // 24576 >= GEMM_SMEM 17408
  int b = blockIdx.x;
  if (b < BINB) bin_body(smem, b, src, dst, bins, gcur);
  else gemm_body(smem, (b - BINB) * 4, x, W1, hs);
}

// dispatch 2: csr fill (196 blocks, big LDS stage)
__global__ __launch_bounds__(256) void k_pre2(const int* __restrict__ bins, const int* __restrict__ gcur,
                                              int* __restrict__ rowptr, float* __restrict__ dinv,
                                              int* __restrict__ csr) {
  __shared__ __align__(16) char smem[FILL_SMEM];
  fill_body(smem, blockIdx.x, bins, gcur, rowptr, dinv, csr);
}

// standalone fallback wrappers (ws too small to un-alias bins)
__global__ __launch_bounds__(256) void k_bin2(const int* src, const int* dst, int* bins, int* gcur) {
  __shared__ __align__(16) char smem[BIN_SMEM];
  bin_body(smem, blockIdx.x, src, dst, bins, gcur);
}
__global__ __launch_bounds__(256) void k_fillb2(const int* bins, const int* gcur, int* rowptr,
                                                float* dinv, int* csr) {
  __shared__ __align__(16) char smem[FILL_SMEM];
  fill_body(smem, blockIdx.x, bins, gcur, rowptr, dinv, csr);
}
__global__ __launch_bounds__(256) void k_gemm(const float* x, const float* W, short* hs) {
  __shared__ __align__(16) char smem[GEMM_SMEM];
  gemm_body(smem, blockIdx.x * 4, x, W, hs);
}

extern "C" void kernel_launch(void* const* d_in, const int* in_sizes, int n_in,
                              void* d_out, int out_size, void* d_ws, size_t ws_size,
                              hipStream_t stream) {
  const float* x  = (const float*)d_in[0];
  const int* ei   = (const int*)d_in[1];
  const float* W1 = (const float*)d_in[2];
  const float* b1 = (const float*)d_in[3];
  const float* g1 = (const float*)d_in[4];
  const float* be1= (const float*)d_in[5];
  const float* W2 = (const float*)d_in[6];
  const float* b2 = (const float*)d_in[7];
  const float* g2 = (const float*)d_in[8];
  const float* be2= (const float*)d_in[9];
  const float* W3 = (const float*)d_in[10];
  const float* b3 = (const float*)d_in[11];
  const float* g3 = (const float*)d_in[12];
  const float* be3= (const float*)d_in[13];
  const float* Wh = (const float*)d_in[14];
  const float* bh = (const float*)d_in[15];
  const int* srcp = ei;
  const int* dstp = ei + EDGES;

  char* ws = (char*)d_ws;
  size_t off = 0;
  auto take = [&](size_t bytes) {
    char* p = ws + off;
    off = (off + bytes + 255) & ~(size_t)255;
    return p;
  };
  float* dinv = (float*)take((size_t)NODES * 4);
  int* rowptr = (int*)take((size_t)(NODES + 1) * 4);
  int* csr    = (int*)take((size_t)EDGES * 4);
  short* hs_a = (short*)take((size_t)NODES * 64 * 2);   // 12.8 MB
  short* hs_b = (short*)take((size_t)NODES * 64 * 2);   // 12.8 MB

  size_t bins_sz = (size_t)NBUCK * BCAP2 * 4;           // 9.63 MB
  bool overlap = (ws_size >= off + bins_sz + 4096);
  int* bins; int* gcur;
  if (overlap) {
    bins = (int*)take(bins_sz);
    gcur = (int*)take((size_t)NBUCK * 4);
  } else {
    // fall back to aliasing (bins consumed by fill before any GEMM writes hs)
    bins = (int*)hs_a;
    gcur = (int*)hs_b;
  }

  (void)hipMemsetAsync(gcur, 0, (size_t)NBUCK * 4, stream);
  if (overlap) {
    k_pre1<<<BINB + GEMMB, 256, 0, stream>>>(srcp, dstp, bins, gcur, x, W1, hs_a);
    k_pre2<<<NBUCK, 256, 0, stream>>>(bins, gcur, rowptr, dinv, csr);
  } else {
    k_bin2<<<BINB, 256, 0, stream>>>(srcp, dstp, bins, gcur);
    k_fillb2<<<NBUCK, 256, 0, stream>>>(bins, gcur, rowptr, dinv, csr);
    k_gemm<<<GEMMB, 256, 0, stream>>>(x, W1, hs_a);
  }
  // layer 1: hs_a is UNscaled -> gather dinv[src] per edge (weights in agg)
  k_aggg<false><<<NODES / 32, 256, 0, stream>>>(hs_a, dinv, rowptr, csr, b1, g1, be1, W2, hs_b);
  // layers 2/3: producer prescaled rows by dinv
  k_aggg<true><<<NODES / 32, 256, 0, stream>>>(hs_b, dinv, rowptr, csr, b2, g2, be2, W3, hs_a);
  k_agg_fin<<<NODES / 32, 256, 0, stream>>>(hs_a, dinv, rowptr, csr, b3, g3, be3, Wh, bh, (float*)d_out);
}